// Round 9
// baseline (276.524 us; speedup 1.0000x reference)
//
#include <hip/hip_runtime.h>

typedef float floatx4 __attribute__((ext_vector_type(4)));
typedef int intx4 __attribute__((ext_vector_type(4)));

#define GN 4096
#define GK 1024
#define BM 128
#define BN 128
#define BK 64           // K-bytes per LDS step -> 16 iters
#define INVT (1.0f/0.03f)
#define QS 24.0f        // int8 quant scale; dots <= 1024*127^2 < 2^24 (fp32-exact)
#define NTILES 528      // 32*33/2 upper-tri tiles per modality
#define NCROSS 1024     // 32*32 cross tiles
#define NWG (NCROSS + 2 * NTILES)   // 2080

static __device__ __forceinline__ int q8(float x) {
    int v = __float2int_rn(x * QS);
    return v < -127 ? -127 : (v > 127 ? 127 : v);
}

// ONE WAVE PER ROW: no LDS, no __syncthreads, 4 coalesced float4 passes.
__global__ __launch_bounds__(256)
void prep_all(const float* __restrict__ brand, const float* __restrict__ post,
              unsigned char* __restrict__ brandq, unsigned char* __restrict__ postq,
              float* __restrict__ inv_brand, float* __restrict__ inv_post,
              float* __restrict__ dvec, float* __restrict__ accs,
              float* __restrict__ out, int* __restrict__ ticket) {
    const int i = (blockIdx.x << 2) + (threadIdx.x >> 6);   // row 0..4095
    const int lane = threadIdx.x & 63;

    const float4* pRow = (const float4*)(post  + (size_t)i * GK);
    const float4* bRow = (const float4*)(brand + (size_t)i * GK);
    int* pOut = (int*)(postq  + (size_t)i * GK);
    int* bOut = (int*)(brandq + (size_t)i * GK);

    float ssp = 0.f, ssb = 0.f, ssd = 0.f;
    #pragma unroll
    for (int j = 0; j < 4; ++j) {
        const int idx = j * 64 + lane;
        float4 pv = pRow[idx];
        float4 bv = bRow[idx];
        int p0 = q8(pv.x), p1 = q8(pv.y), p2 = q8(pv.z), p3 = q8(pv.w);
        int b0 = q8(bv.x), b1 = q8(bv.y), b2 = q8(bv.z), b3 = q8(bv.w);
        pOut[idx] = (p0 & 255) | ((p1 & 255) << 8) | ((p2 & 255) << 16) | ((p3 & 255) << 24);
        bOut[idx] = (b0 & 255) | ((b1 & 255) << 8) | ((b2 & 255) << 16) | ((b3 & 255) << 24);
        ssp += (float)(p0 * p0 + p1 * p1 + p2 * p2 + p3 * p3);
        ssb += (float)(b0 * b0 + b1 * b1 + b2 * b2 + b3 * b3);
        ssd += (float)(p0 * b0 + p1 * b1 + p2 * b2 + p3 * b3);
    }
    #pragma unroll
    for (int off = 32; off > 0; off >>= 1) {
        ssp += __shfl_down(ssp, off);
        ssb += __shfl_down(ssb, off);
        ssd += __shfl_down(ssd, off);
    }
    if (lane == 0) {
        inv_post[i]  = 1.0f / sqrtf(ssp);
        inv_brand[i] = 1.0f / sqrtf(ssb);
        dvec[i]      = ssd;
    } else if (lane == 1) accs[i] = 0.f;
    else if (lane == 2) accs[GN + i] = 0.f;
    else if (lane == 3) accs[2 * GN + i] = 0.f;
    else if (lane == 4) accs[3 * GN + i] = 0.f;
    else if (lane == 5 && i == 0) out[0] = 0.f;
    else if (lane == 6 && i == 0) ticket[0] = 0;
}

// Unified GEMM, int8 16x16x64 MFMA. R8 base (counted vmcnt, A triple/B double
// buffers, 40KB LDS, 4 blocks/CU, 128x128 tile, 64x64/wave) + two additions:
//  - T5 s_setprio(1) around the MFMA cluster (4 independent blocks/CU at
//    staggered phases = the regime where setprio paid on attn, m191).
//  - final_loss FUSED via last-block ticket: per-thread threadfence ->
//    __syncthreads -> tid0 atomicAdd(ticket); winner block re-reads the
//    accumulators with agent-scope atomic loads and writes out[0].
#define AS1C (const __attribute__((address_space(1))) void*)
#define AS3C (__attribute__((address_space(3))) void*)

#define STAGE_A(b, k0) do { \
    unsigned char* _d = smem + (b) * 8192 + wave * 2048; \
    __builtin_amdgcn_global_load_lds(AS1C(aSrc + (k0)),           AS3C(_d),        16, 0, 0); \
    __builtin_amdgcn_global_load_lds(AS1C(aSrc + 16 * GK + (k0)), AS3C(_d + 1024), 16, 0, 0); \
} while (0)
#define STAGE_B(b, k0) do { \
    unsigned char* _d = smem + 24576 + (b) * 8192 + wave * 2048; \
    __builtin_amdgcn_global_load_lds(AS1C(bSrc + (k0)),           AS3C(_d),        16, 0, 0); \
    __builtin_amdgcn_global_load_lds(AS1C(bSrc + 16 * GK + (k0)), AS3C(_d + 1024), 16, 0, 0); \
} while (0)

#define KITER(a, b) do { \
    const unsigned char* As_ = smem + (a) * 8192; \
    const unsigned char* Bs_ = smem + 24576 + (b) * 8192; \
    intx4 af[4], bfr[4]; \
    _Pragma("unroll") \
    for (int _u = 0; _u < 4; ++_u) \
        bfr[_u] = *(const intx4*)(Bs_ + bOff + _u * 1024); \
    _Pragma("unroll") \
    for (int _m = 0; _m < 4; ++_m) \
        af[_m] = *(const intx4*)(As_ + aOff + _m * 1024); \
    __builtin_amdgcn_s_setprio(1); \
    _Pragma("unroll") \
    for (int _t = 0; _t < 4; ++_t) \
        _Pragma("unroll") \
        for (int _u = 0; _u < 4; ++_u) \
            acc[_t][_u] = __builtin_amdgcn_mfma_i32_16x16x64_i8( \
                af[_t], bfr[_u], acc[_t][_u], 0, 0, 0); \
    __builtin_amdgcn_s_setprio(0); \
} while (0)

#define VM2BAR() asm volatile("s_waitcnt vmcnt(2)\n\ts_barrier" ::: "memory")
#define VM0BAR() asm volatile("s_waitcnt vmcnt(0)\n\ts_barrier" ::: "memory")

__global__ __launch_bounds__(256, 4)
void gemm_all(const unsigned char* __restrict__ postq, const unsigned char* __restrict__ brandq,
              const float* __restrict__ dvec,
              const float* __restrict__ inv_post, const float* __restrict__ inv_brand,
              float* __restrict__ sum_post, float* __restrict__ cnt_post,
              float* __restrict__ sum_brand, float* __restrict__ cnt_brand,
              float* __restrict__ out, int* __restrict__ ticket) {
    __shared__ __align__(16) unsigned char smem[(3 + 2) * BM * BK];   // 40 KB; epilogue alias

    const int tid = threadIdx.x;
    const int wave = tid >> 6, lane = tid & 63;
    const int wm = (wave >> 1) * 64, wn = (wave & 1) * 64;

    int idx = blockIdx.x;

    const unsigned char *A, *B;
    const float *invA, *invB;
    float *srow, *scol, *crow, *ccol;
    int bm, bn;
    float iaScale;
    bool is_cross, do_cols;

    if (idx < NCROSS) {
        is_cross = true; do_cols = true;
        bm = (idx >> 5) * BM; bn = (idx & 31) * BN;
        A = postq; B = brandq;
        invA = inv_post; invB = inv_brand; iaScale = INVT;
        srow = sum_post; crow = cnt_post; scol = sum_brand; ccol = cnt_brand;
    } else {
        is_cross = false;
        idx -= NCROSS;
        const unsigned char* X; const float* invx; float* sacc;
        if (idx >= NTILES) { idx -= NTILES; X = brandq; invx = inv_brand; sacc = sum_brand; }
        else               {               X = postq;  invx = inv_post;  sacc = sum_post;  }
        int J = (int)((sqrtf(8.f * idx + 1.f) - 1.f) * 0.5f);
        while ((J + 1) * (J + 2) / 2 <= idx) ++J;
        while (J * (J + 1) / 2 > idx) --J;
        const int I = idx - J * (J + 1) / 2;
        bm = I * BM; bn = J * BN;
        A = X; B = X;
        invA = invx; invB = invx; iaScale = 0.8f * INVT;
        srow = sacc; scol = sacc; crow = nullptr; ccol = nullptr;
        do_cols = (I != J);
    }

    const int lrow = lane & 15;
    const int kq = lane >> 4;                 // 0..3

    // DMA: lane l -> row l>>2 (16 rows/instr), LDS slot l&3 (linear dest),
    // global chunk (l&3)^((l>>4)&3) = slot ^ ((row>>2)&3), row = base16 + (l>>2).
    const size_t dma_off = (size_t)(lane >> 2) * GK
                         + ((((lane & 3) ^ ((lane >> 4) & 3))) * 16);
    const unsigned char* aSrc = A + (size_t)(bm + wave * 32) * GK + dma_off;
    const unsigned char* bSrc = B + (size_t)(bn + wave * 32) * GK + dma_off;

    // fragment read: row = (wm|wn) + m*16 + lrow -> (row>>2)&3 = (lrow>>2)&3
    const int cx = ((kq ^ ((lrow >> 2) & 3)) * 16);
    const int aOff = (wm + lrow) * BK + cx;
    const int bOff = (wn + lrow) * BK + cx;

    intx4 acc[4][4] = {};

    // prologue: B(0)->b0, A(0)->a0, A(1)->a1; retire B0+A0, leave A1 in flight
    STAGE_B(0, 0); STAGE_A(0, 0); STAGE_A(1, 64);
    VM2BAR();

    // steady state: t = 0..11 (A bufs t%3, B bufs t&1; period lcm = 6)
    #pragma unroll 1
    for (int k = 0; k < 768; k += 384) {
        STAGE_B(1, k +  64); STAGE_A(2, k + 128); KITER(0, 0); VM2BAR();
        STAGE_B(0, k + 128); STAGE_A(0, k + 192); KITER(1, 1); VM2BAR();
        STAGE_B(1, k + 192); STAGE_A(1, k + 256); KITER(2, 0); VM2BAR();
        STAGE_B(0, k + 256); STAGE_A(2, k + 320); KITER(0, 1); VM2BAR();
        STAGE_B(1, k + 320); STAGE_A(0, k + 384); KITER(1, 0); VM2BAR();
        STAGE_B(0, k + 384); STAGE_A(1, k + 448); KITER(2, 1); VM2BAR();
    }
    // tail: t = 12..15
    STAGE_B(1, 832); STAGE_A(2, 896); KITER(0, 0); VM2BAR();   // t=12
    STAGE_B(0, 896); STAGE_A(0, 960); KITER(1, 1); VM2BAR();   // t=13
    STAGE_B(1, 960);                  KITER(2, 0); VM0BAR();   // t=14
                                      KITER(0, 1);             // t=15
    __syncthreads();                  // separates tile reads from epilogue alias

    // ---- epilogue (C/D: col=lane&15, row=(lane>>4)*4+reg; shape-determined) ----
    const int cn = lane & 15, rq = lane >> 4;
    float ib_c[4], db_c[4];
    #pragma unroll
    for (int u = 0; u < 4; ++u) {
        const int gc = bn + wn + u * 16 + cn;
        ib_c[u] = invB[gc];
        db_c[u] = is_cross ? dvec[gc] : 0.f;
    }

    float csum[4] = {}, ccnt[4] = {};
    float my_rs = 0.f, my_rc = 0.f;
    #pragma unroll
    for (int t = 0; t < 4; ++t) {
        #pragma unroll
        for (int r = 0; r < 4; ++r) {
            const int rl = wm + t * 16 + rq * 4 + r;
            const int grow = bm + rl;
            const float ia = invA[grow] * iaScale;
            float v = 0.f, w = 0.f;
            if (is_cross) {
                const float da = dvec[grow];
                #pragma unroll
                for (int u = 0; u < 4; ++u) {
                    const float s = (float)acc[t][u][r];   // exact int < 2^24
                    const int gcol = bn + wn + u * 16 + cn;
                    const bool diag = (grow == gcol);
                    float e = __expf(s * ia * ib_c[u]);
                    v += e;
                    csum[u] += e;
                    w += (!diag && s > da) ? 1.f : 0.f;
                    ccnt[u] += (!diag && s > db_c[u]) ? 1.f : 0.f;
                }
                w += __shfl_xor(w, 1); w += __shfl_xor(w, 2);
                w += __shfl_xor(w, 4); w += __shfl_xor(w, 8);
            } else {
                #pragma unroll
                for (int u = 0; u < 4; ++u) {
                    const float s = (float)acc[t][u][r];
                    const int gcol = bn + wn + u * 16 + cn;
                    float e = (grow == gcol) ? 1.0f : __expf(s * ia * ib_c[u]);
                    v += e;
                    csum[u] += e;
                }
            }
            v += __shfl_xor(v, 1); v += __shfl_xor(v, 2);
            v += __shfl_xor(v, 4); v += __shfl_xor(v, 8);
            if (cn == ((t << 2) | r)) { my_rs = v; my_rc = w; }
        }
    }

    // reduction scratch aliases the (dead) tile LDS
    float (*redRS)[2] = (float(*)[2])(smem);
    float (*redRC)[2] = (float(*)[2])(smem + 1024);
    float (*redCS)[2] = (float(*)[2])(smem + 2048);
    float (*redCC)[2] = (float(*)[2])(smem + 3072);

    const int rl_local = wm + (cn >> 2) * 16 + rq * 4 + (cn & 3);
    redRS[rl_local][wave & 1] = my_rs;
    redRC[rl_local][wave & 1] = my_rc;

    float my_cs = 0.f, my_cc = 0.f;
    #pragma unroll
    for (int u = 0; u < 4; ++u) {
        float v = csum[u];
        v += __shfl_xor(v, 16); v += __shfl_xor(v, 32);
        if (rq == u) my_cs = v;
        if (is_cross) {
            float w = ccnt[u];
            w += __shfl_xor(w, 16); w += __shfl_xor(w, 32);
            if (rq == u) my_cc = w;
        }
    }
    const int cl_local = wn + rq * 16 + cn;
    redCS[cl_local][wave >> 1] = my_cs;
    redCC[cl_local][wave >> 1] = my_cc;
    __syncthreads();

    if (tid < 128) {
        atomicAdd(&srow[bm + tid], redRS[tid][0] + redRS[tid][1]);
        if (is_cross) atomicAdd(&crow[bm + tid], redRC[tid][0] + redRC[tid][1]);
    } else if (do_cols) {
        const int t2 = tid - 128;
        atomicAdd(&scol[bn + t2], redCS[t2][0] + redCS[t2][1]);
        if (is_cross) atomicAdd(&ccol[bn + t2], redCC[t2][0] + redCC[t2][1]);
    }

    // ---- fused final_loss: last block to finish computes the global sum ----
    __threadfence();                       // each thread's atomics visible
    __syncthreads();                       // all threads fenced before ticket
    int* flag = (int*)(smem + 8192);
    if (tid == 0) *flag = (atomicAdd(ticket, 1) == NWG - 1) ? 1 : 0;
    __syncthreads();                       // flag uniform across block
    if (*flag) {
        float part = 0.f;
        #pragma unroll
        for (int j = 0; j < 16; ++j) {
            const int i = j * 256 + tid;
            float sp = __hip_atomic_load(&sum_post[i],  __ATOMIC_RELAXED, __HIP_MEMORY_SCOPE_AGENT);
            float cp = __hip_atomic_load(&cnt_post[i],  __ATOMIC_RELAXED, __HIP_MEMORY_SCOPE_AGENT);
            float sb = __hip_atomic_load(&sum_brand[i], __ATOMIC_RELAXED, __HIP_MEMORY_SCOPE_AGENT);
            float cb = __hip_atomic_load(&cnt_brand[i], __ATOMIC_RELAXED, __HIP_MEMORY_SCOPE_AGENT);
            float dl = dvec[i] * inv_post[i] * inv_brand[i] * INVT;
            float rp = 1.0f / (4096.0f - cp) + 1.0f;
            float rb = 1.0f / (4096.0f - cb) + 1.0f;
            part += 0.5f * (rb * (logf(sb) - dl) + rp * (logf(sp) - dl));
        }
        #pragma unroll
        for (int off = 32; off > 0; off >>= 1) part += __shfl_down(part, off);
        float* sw = (float*)(smem + 8256);
        if (lane == 0) sw[wave] = part;
        __syncthreads();
        if (tid == 0) out[0] = sw[0] + sw[1] + sw[2] + sw[3];
    }
}

extern "C" void kernel_launch(void* const* d_in, const int* in_sizes, int n_in,
                              void* d_out, int out_size, void* d_ws, size_t ws_size,
                              hipStream_t stream) {
    const float* brand = (const float*)d_in[0];
    const float* post  = (const float*)d_in[1];
    float* out = (float*)d_out;

    char* ws = (char*)d_ws;
    unsigned char* postq  = (unsigned char*)ws;                          // 4 MB
    unsigned char* brandq = postq + (size_t)GN * GK;                     // 4 MB
    float* inv_post  = (float*)(brandq + (size_t)GN * GK);
    float* inv_brand = inv_post + GN;
    float* dvec      = inv_brand + GN;
    float* accs      = dvec + GN;        // [sum_post, sum_brand, cnt_post, cnt_brand]
    float* sum_post  = accs;
    float* sum_brand = accs + GN;
    float* cnt_post  = accs + 2 * GN;
    float* cnt_brand = accs + 3 * GN;
    int*   ticket    = (int*)(accs + 4 * GN);

    prep_all<<<GN / 4, 256, 0, stream>>>(brand, post, brandq, postq,
                                         inv_brand, inv_post, dvec, accs, out, ticket);
    gemm_all<<<NWG, 256, 0, stream>>>(postq, brandq, dvec,
                                      inv_post, inv_brand,
                                      sum_post, cnt_post,
                                      sum_brand, cnt_brand,
                                      out, ticket);
}

// Round 10
// 131.831 us; speedup vs baseline: 2.0976x; 2.0976x over previous
//
#include <hip/hip_runtime.h>

typedef float floatx4 __attribute__((ext_vector_type(4)));
typedef int intx4 __attribute__((ext_vector_type(4)));

#define GN 4096
#define GK 1024
#define BM 128
#define BN 128
#define BK 64           // K-bytes per LDS step -> 16 iters
#define INVT (1.0f/0.03f)
#define QS 24.0f        // int8 quant scale; dots <= 1024*127^2 < 2^24 (fp32-exact)
#define NTILES 528      // 32*33/2 upper-tri tiles per modality
#define NCROSS 1024     // 32*32 cross tiles
#define NWG (NCROSS + 2 * NTILES)   // 2080

static __device__ __forceinline__ int q8(float x) {
    int v = __float2int_rn(x * QS);
    return v < -127 ? -127 : (v > 127 ? 127 : v);
}

// ONE WAVE PER ROW: no LDS, no __syncthreads, 4 coalesced float4 passes.
__global__ __launch_bounds__(256)
void prep_all(const float* __restrict__ brand, const float* __restrict__ post,
              unsigned char* __restrict__ brandq, unsigned char* __restrict__ postq,
              float* __restrict__ inv_brand, float* __restrict__ inv_post,
              float* __restrict__ dvec, float* __restrict__ accs,
              float* __restrict__ out) {
    const int i = (blockIdx.x << 2) + (threadIdx.x >> 6);   // row 0..4095
    const int lane = threadIdx.x & 63;

    const float4* pRow = (const float4*)(post  + (size_t)i * GK);
    const float4* bRow = (const float4*)(brand + (size_t)i * GK);
    int* pOut = (int*)(postq  + (size_t)i * GK);
    int* bOut = (int*)(brandq + (size_t)i * GK);

    float ssp = 0.f, ssb = 0.f, ssd = 0.f;
    #pragma unroll
    for (int j = 0; j < 4; ++j) {
        const int idx = j * 64 + lane;
        float4 pv = pRow[idx];
        float4 bv = bRow[idx];
        int p0 = q8(pv.x), p1 = q8(pv.y), p2 = q8(pv.z), p3 = q8(pv.w);
        int b0 = q8(bv.x), b1 = q8(bv.y), b2 = q8(bv.z), b3 = q8(bv.w);
        pOut[idx] = (p0 & 255) | ((p1 & 255) << 8) | ((p2 & 255) << 16) | ((p3 & 255) << 24);
        bOut[idx] = (b0 & 255) | ((b1 & 255) << 8) | ((b2 & 255) << 16) | ((b3 & 255) << 24);
        ssp += (float)(p0 * p0 + p1 * p1 + p2 * p2 + p3 * p3);
        ssb += (float)(b0 * b0 + b1 * b1 + b2 * b2 + b3 * b3);
        ssd += (float)(p0 * b0 + p1 * b1 + p2 * b2 + p3 * b3);
    }
    #pragma unroll
    for (int off = 32; off > 0; off >>= 1) {
        ssp += __shfl_down(ssp, off);
        ssb += __shfl_down(ssb, off);
        ssd += __shfl_down(ssd, off);
    }
    if (lane == 0) {
        inv_post[i]  = 1.0f / sqrtf(ssp);
        inv_brand[i] = 1.0f / sqrtf(ssb);
        dvec[i]      = ssd;
    } else if (lane == 1) accs[i] = 0.f;
    else if (lane == 2) accs[GN + i] = 0.f;
    else if (lane == 3) accs[2 * GN + i] = 0.f;
    else if (lane == 4) accs[3 * GN + i] = 0.f;
    else if (lane == 5 && i == 0) out[0] = 0.f;
}

// Unified GEMM, int8 16x16x64 MFMA. === EXACT R8 (best measured: gemm 60.8us,
// total 130.9us) ===. Counted vmcnt, A triple-buffered (3x8K, depth-2
// prefetch), B double-buffered (2x8K, one-KITER cover), 40KB LDS ->
// 4 blocks/CU, 128x128 tile, 64x64/wave, regs capped via launch_bounds(256,4).
// R9 lesson: NO setprio around MFMA (starves staging waves at 16 waves/CU),
// NO fused final via threadfence ticket (per-block device fence = L2 drain,
// +150us). Per iter: {STAGE_B(t+1) -> STAGE_A(t+2) -> KITER(t) -> vmcnt(2);
// barrier} - wait retires A(t+1)+B(t+1), leaves A(t+2) in flight.
#define AS1C (const __attribute__((address_space(1))) void*)
#define AS3C (__attribute__((address_space(3))) void*)

#define STAGE_A(b, k0) do { \
    unsigned char* _d = smem + (b) * 8192 + wave * 2048; \
    __builtin_amdgcn_global_load_lds(AS1C(aSrc + (k0)),           AS3C(_d),        16, 0, 0); \
    __builtin_amdgcn_global_load_lds(AS1C(aSrc + 16 * GK + (k0)), AS3C(_d + 1024), 16, 0, 0); \
} while (0)
#define STAGE_B(b, k0) do { \
    unsigned char* _d = smem + 24576 + (b) * 8192 + wave * 2048; \
    __builtin_amdgcn_global_load_lds(AS1C(bSrc + (k0)),           AS3C(_d),        16, 0, 0); \
    __builtin_amdgcn_global_load_lds(AS1C(bSrc + 16 * GK + (k0)), AS3C(_d + 1024), 16, 0, 0); \
} while (0)

#define KITER(a, b) do { \
    const unsigned char* As_ = smem + (a) * 8192; \
    const unsigned char* Bs_ = smem + 24576 + (b) * 8192; \
    intx4 af[4], bfr[4]; \
    _Pragma("unroll") \
    for (int _u = 0; _u < 4; ++_u) \
        bfr[_u] = *(const intx4*)(Bs_ + bOff + _u * 1024); \
    _Pragma("unroll") \
    for (int _m = 0; _m < 4; ++_m) \
        af[_m] = *(const intx4*)(As_ + aOff + _m * 1024); \
    _Pragma("unroll") \
    for (int _t = 0; _t < 4; ++_t) \
        _Pragma("unroll") \
        for (int _u = 0; _u < 4; ++_u) \
            acc[_t][_u] = __builtin_amdgcn_mfma_i32_16x16x64_i8( \
                af[_t], bfr[_u], acc[_t][_u], 0, 0, 0); \
} while (0)

#define VM2BAR() asm volatile("s_waitcnt vmcnt(2)\n\ts_barrier" ::: "memory")
#define VM0BAR() asm volatile("s_waitcnt vmcnt(0)\n\ts_barrier" ::: "memory")

__global__ __launch_bounds__(256, 4)
void gemm_all(const unsigned char* __restrict__ postq, const unsigned char* __restrict__ brandq,
              const float* __restrict__ dvec,
              const float* __restrict__ inv_post, const float* __restrict__ inv_brand,
              float* __restrict__ sum_post, float* __restrict__ cnt_post,
              float* __restrict__ sum_brand, float* __restrict__ cnt_brand) {
    __shared__ __align__(16) unsigned char smem[(3 + 2) * BM * BK];   // 40 KB; epilogue alias

    const int tid = threadIdx.x;
    const int wave = tid >> 6, lane = tid & 63;
    const int wm = (wave >> 1) * 64, wn = (wave & 1) * 64;

    int idx = blockIdx.x;

    const unsigned char *A, *B;
    const float *invA, *invB;
    float *srow, *scol, *crow, *ccol;
    int bm, bn;
    float iaScale;
    bool is_cross, do_cols;

    if (idx < NCROSS) {
        is_cross = true; do_cols = true;
        bm = (idx >> 5) * BM; bn = (idx & 31) * BN;
        A = postq; B = brandq;
        invA = inv_post; invB = inv_brand; iaScale = INVT;
        srow = sum_post; crow = cnt_post; scol = sum_brand; ccol = cnt_brand;
    } else {
        is_cross = false;
        idx -= NCROSS;
        const unsigned char* X; const float* invx; float* sacc;
        if (idx >= NTILES) { idx -= NTILES; X = brandq; invx = inv_brand; sacc = sum_brand; }
        else               {               X = postq;  invx = inv_post;  sacc = sum_post;  }
        int J = (int)((sqrtf(8.f * idx + 1.f) - 1.f) * 0.5f);
        while ((J + 1) * (J + 2) / 2 <= idx) ++J;
        while (J * (J + 1) / 2 > idx) --J;
        const int I = idx - J * (J + 1) / 2;
        bm = I * BM; bn = J * BN;
        A = X; B = X;
        invA = invx; invB = invx; iaScale = 0.8f * INVT;
        srow = sacc; scol = sacc; crow = nullptr; ccol = nullptr;
        do_cols = (I != J);
    }

    const int lrow = lane & 15;
    const int kq = lane >> 4;                 // 0..3

    // DMA: lane l -> row l>>2 (16 rows/instr), LDS slot l&3 (linear dest),
    // global chunk (l&3)^((l>>4)&3) = slot ^ ((row>>2)&3), row = base16 + (l>>2).
    const size_t dma_off = (size_t)(lane >> 2) * GK
                         + ((((lane & 3) ^ ((lane >> 4) & 3))) * 16);
    const unsigned char* aSrc = A + (size_t)(bm + wave * 32) * GK + dma_off;
    const unsigned char* bSrc = B + (size_t)(bn + wave * 32) * GK + dma_off;

    // fragment read: row = (wm|wn) + m*16 + lrow -> (row>>2)&3 = (lrow>>2)&3
    const int cx = ((kq ^ ((lrow >> 2) & 3)) * 16);
    const int aOff = (wm + lrow) * BK + cx;
    const int bOff = (wn + lrow) * BK + cx;

    intx4 acc[4][4] = {};

    // prologue: B(0)->b0, A(0)->a0, A(1)->a1; retire B0+A0, leave A1 in flight
    STAGE_B(0, 0); STAGE_A(0, 0); STAGE_A(1, 64);
    VM2BAR();

    // steady state: t = 0..11 (A bufs t%3, B bufs t&1; period lcm = 6)
    #pragma unroll 1
    for (int k = 0; k < 768; k += 384) {
        STAGE_B(1, k +  64); STAGE_A(2, k + 128); KITER(0, 0); VM2BAR();
        STAGE_B(0, k + 128); STAGE_A(0, k + 192); KITER(1, 1); VM2BAR();
        STAGE_B(1, k + 192); STAGE_A(1, k + 256); KITER(2, 0); VM2BAR();
        STAGE_B(0, k + 256); STAGE_A(2, k + 320); KITER(0, 1); VM2BAR();
        STAGE_B(1, k + 320); STAGE_A(0, k + 384); KITER(1, 0); VM2BAR();
        STAGE_B(0, k + 384); STAGE_A(1, k + 448); KITER(2, 1); VM2BAR();
    }
    // tail: t = 12..15
    STAGE_B(1, 832); STAGE_A(2, 896); KITER(0, 0); VM2BAR();   // t=12
    STAGE_B(0, 896); STAGE_A(0, 960); KITER(1, 1); VM2BAR();   // t=13
    STAGE_B(1, 960);                  KITER(2, 0); VM0BAR();   // t=14
                                      KITER(0, 1);             // t=15
    __syncthreads();                  // separates tile reads from epilogue alias

    // ---- epilogue (C/D: col=lane&15, row=(lane>>4)*4+reg; shape-determined) ----
    const int cn = lane & 15, rq = lane >> 4;
    float ib_c[4], db_c[4];
    #pragma unroll
    for (int u = 0; u < 4; ++u) {
        const int gc = bn + wn + u * 16 + cn;
        ib_c[u] = invB[gc];
        db_c[u] = is_cross ? dvec[gc] : 0.f;
    }

    float csum[4] = {}, ccnt[4] = {};
    float my_rs = 0.f, my_rc = 0.f;
    #pragma unroll
    for (int t = 0; t < 4; ++t) {
        #pragma unroll
        for (int r = 0; r < 4; ++r) {
            const int rl = wm + t * 16 + rq * 4 + r;
            const int grow = bm + rl;
            const float ia = invA[grow] * iaScale;
            float v = 0.f, w = 0.f;
            if (is_cross) {
                const float da = dvec[grow];
                #pragma unroll
                for (int u = 0; u < 4; ++u) {
                    const float s = (float)acc[t][u][r];   // exact int < 2^24
                    const int gcol = bn + wn + u * 16 + cn;
                    const bool diag = (grow == gcol);
                    float e = __expf(s * ia * ib_c[u]);
                    v += e;
                    csum[u] += e;
                    w += (!diag && s > da) ? 1.f : 0.f;
                    ccnt[u] += (!diag && s > db_c[u]) ? 1.f : 0.f;
                }
                w += __shfl_xor(w, 1); w += __shfl_xor(w, 2);
                w += __shfl_xor(w, 4); w += __shfl_xor(w, 8);
            } else {
                #pragma unroll
                for (int u = 0; u < 4; ++u) {
                    const float s = (float)acc[t][u][r];
                    const int gcol = bn + wn + u * 16 + cn;
                    float e = (grow == gcol) ? 1.0f : __expf(s * ia * ib_c[u]);
                    v += e;
                    csum[u] += e;
                }
            }
            v += __shfl_xor(v, 1); v += __shfl_xor(v, 2);
            v += __shfl_xor(v, 4); v += __shfl_xor(v, 8);
            if (cn == ((t << 2) | r)) { my_rs = v; my_rc = w; }
        }
    }

    // reduction scratch aliases the (dead) tile LDS
    float (*redRS)[2] = (float(*)[2])(smem);
    float (*redRC)[2] = (float(*)[2])(smem + 1024);
    float (*redCS)[2] = (float(*)[2])(smem + 2048);
    float (*redCC)[2] = (float(*)[2])(smem + 3072);

    const int rl_local = wm + (cn >> 2) * 16 + rq * 4 + (cn & 3);
    redRS[rl_local][wave & 1] = my_rs;
    redRC[rl_local][wave & 1] = my_rc;

    float my_cs = 0.f, my_cc = 0.f;
    #pragma unroll
    for (int u = 0; u < 4; ++u) {
        float v = csum[u];
        v += __shfl_xor(v, 16); v += __shfl_xor(v, 32);
        if (rq == u) my_cs = v;
        if (is_cross) {
            float w = ccnt[u];
            w += __shfl_xor(w, 16); w += __shfl_xor(w, 32);
            if (rq == u) my_cc = w;
        }
    }
    const int cl_local = wn + rq * 16 + cn;
    redCS[cl_local][wave >> 1] = my_cs;
    redCC[cl_local][wave >> 1] = my_cc;
    __syncthreads();

    if (tid < 128) {
        atomicAdd(&srow[bm + tid], redRS[tid][0] + redRS[tid][1]);
        if (is_cross) atomicAdd(&crow[bm + tid], redRC[tid][0] + redRC[tid][1]);
    } else if (do_cols) {
        const int t2 = tid - 128;
        atomicAdd(&scol[bn + t2], redCS[t2][0] + redCS[t2][1]);
        if (is_cross) atomicAdd(&ccol[bn + t2], redCC[t2][0] + redCC[t2][1]);
    }
}

// Final per-row loss assembly + global sum
__global__ __launch_bounds__(256)
void final_loss(const float* __restrict__ sum_post, const float* __restrict__ cnt_post,
                const float* __restrict__ sum_brand, const float* __restrict__ cnt_brand,
                const float* __restrict__ dvec,
                const float* __restrict__ inv_post, const float* __restrict__ inv_brand,
                float* __restrict__ out) {
    const int i = blockIdx.x * 256 + threadIdx.x;
    float dl = dvec[i] * inv_post[i] * inv_brand[i] * INVT;
    float lp = logf(sum_post[i]);
    float lb = logf(sum_brand[i]);
    float rp = 1.0f / (4096.0f - cnt_post[i]) + 1.0f;
    float rb = 1.0f / (4096.0f - cnt_brand[i]) + 1.0f;
    float loss = 0.5f * (rb * (lb - dl) + rp * (lp - dl));
    #pragma unroll
    for (int off = 32; off > 0; off >>= 1) loss += __shfl_down(loss, off);
    __shared__ float sw[4];
    int wave = threadIdx.x >> 6, lane = threadIdx.x & 63;
    if (lane == 0) sw[wave] = loss;
    __syncthreads();
    if (threadIdx.x == 0) atomicAdd(out, sw[0] + sw[1] + sw[2] + sw[3]);
}

extern "C" void kernel_launch(void* const* d_in, const int* in_sizes, int n_in,
                              void* d_out, int out_size, void* d_ws, size_t ws_size,
                              hipStream_t stream) {
    const float* brand = (const float*)d_in[0];
    const float* post  = (const float*)d_in[1];
    float* out = (float*)d_out;

    char* ws = (char*)d_ws;
    unsigned char* postq  = (unsigned char*)ws;                          // 4 MB
    unsigned char* brandq = postq + (size_t)GN * GK;                     // 4 MB
    float* inv_post  = (float*)(brandq + (size_t)GN * GK);
    float* inv_brand = inv_post + GN;
    float* dvec      = inv_brand + GN;
    float* accs      = dvec + GN;        // [sum_post, sum_brand, cnt_post, cnt_brand]
    float* sum_post  = accs;
    float* sum_brand = accs + GN;
    float* cnt_post  = accs + 2 * GN;
    float* cnt_brand = accs + 3 * GN;

    prep_all<<<GN / 4, 256, 0, stream>>>(brand, post, brandq, postq,
                                         inv_brand, inv_post, dvec, accs, out);
    gemm_all<<<NWG, 256, 0, stream>>>(postq, brandq, dvec,
                                      inv_post, inv_brand,
                                      sum_post, cnt_post,
                                      sum_brand, cnt_brand);
    final_loss<<<GN / 256, 256, 0, stream>>>(sum_post, cnt_post, sum_brand, cnt_brand,
                                             dvec, inv_post, inv_brand, out);
}

// Round 11
// 131.330 us; speedup vs baseline: 2.1056x; 1.0038x over previous
//
#include <hip/hip_runtime.h>

typedef float floatx4 __attribute__((ext_vector_type(4)));
typedef int intx4 __attribute__((ext_vector_type(4)));

#define GN 4096
#define GK 1024
#define BM 128
#define BN 128
#define BK 64           // K-bytes per LDS step -> 16 iters
#define INVT (1.0f/0.03f)
#define QS 24.0f        // int8 quant scale; dots <= 1024*127^2 < 2^24 (fp32-exact)
#define NTILES 528      // 32*33/2 upper-tri tiles per modality
#define NCROSS 1024     // 32*32 cross tiles
#define NWG (NCROSS + 2 * NTILES)   // 2080

static __device__ __forceinline__ int q8(float x) {
    int v = __float2int_rn(x * QS);
    return v < -127 ? -127 : (v > 127 ? 127 : v);
}

// ONE WAVE PER ROW: no LDS, no __syncthreads, 4 coalesced float4 passes.
__global__ __launch_bounds__(256)
void prep_all(const float* __restrict__ brand, const float* __restrict__ post,
              unsigned char* __restrict__ brandq, unsigned char* __restrict__ postq,
              float* __restrict__ inv_brand, float* __restrict__ inv_post,
              float* __restrict__ dvec, float* __restrict__ accs,
              float* __restrict__ out) {
    const int i = (blockIdx.x << 2) + (threadIdx.x >> 6);   // row 0..4095
    const int lane = threadIdx.x & 63;

    const float4* pRow = (const float4*)(post  + (size_t)i * GK);
    const float4* bRow = (const float4*)(brand + (size_t)i * GK);
    int* pOut = (int*)(postq  + (size_t)i * GK);
    int* bOut = (int*)(brandq + (size_t)i * GK);

    float ssp = 0.f, ssb = 0.f, ssd = 0.f;
    #pragma unroll
    for (int j = 0; j < 4; ++j) {
        const int idx = j * 64 + lane;
        float4 pv = pRow[idx];
        float4 bv = bRow[idx];
        int p0 = q8(pv.x), p1 = q8(pv.y), p2 = q8(pv.z), p3 = q8(pv.w);
        int b0 = q8(bv.x), b1 = q8(bv.y), b2 = q8(bv.z), b3 = q8(bv.w);
        pOut[idx] = (p0 & 255) | ((p1 & 255) << 8) | ((p2 & 255) << 16) | ((p3 & 255) << 24);
        bOut[idx] = (b0 & 255) | ((b1 & 255) << 8) | ((b2 & 255) << 16) | ((b3 & 255) << 24);
        ssp += (float)(p0 * p0 + p1 * p1 + p2 * p2 + p3 * p3);
        ssb += (float)(b0 * b0 + b1 * b1 + b2 * b2 + b3 * b3);
        ssd += (float)(p0 * b0 + p1 * b1 + p2 * b2 + p3 * b3);
    }
    #pragma unroll
    for (int off = 32; off > 0; off >>= 1) {
        ssp += __shfl_down(ssp, off);
        ssb += __shfl_down(ssb, off);
        ssd += __shfl_down(ssd, off);
    }
    if (lane == 0) {
        inv_post[i]  = 1.0f / sqrtf(ssp);
        inv_brand[i] = 1.0f / sqrtf(ssb);
        dvec[i]      = ssd;
    } else if (lane == 1) accs[i] = 0.f;
    else if (lane == 2) accs[GN + i] = 0.f;
    else if (lane == 3) accs[2 * GN + i] = 0.f;
    else if (lane == 4) accs[3 * GN + i] = 0.f;
    else if (lane == 5 && i == 0) out[0] = 0.f;
}

// Unified GEMM, int8 16x16x64 MFMA. R8 structure (counted vmcnt, A triple/
// B double buffers, 40KB LDS, 4 blocks/CU, 128x128, 64x64/wave) with the
// bank swizzle CORRECTED: ds_read_b128 services 8 lanes x 16B = 32 banks per
// cycle; bank-start of (row,chunk) = 16*(row&1) + 4*chunk, so the 8 rows of
// a service group need chunk XOR'd by ((row>>1)&3) (4 distinct values over
// even rows / odd rows) to cover all 8 bank-quads. R4/R8 used (row>>2)&3 and
// R3 used (row&3) - BOTH are exactly 2-way quad-aliased on every read, which
// is why all measured the identical 4,392,960 conflicts (and R5's B-only
// exactly half). Fix is read chunk = kq ^ ((row>>1)&3), DMA global chunk =
// slot ^ ((row>>1)&3) = (l&3)^((l>>3)&3); DMA dest stays linear.
#define AS1C (const __attribute__((address_space(1))) void*)
#define AS3C (__attribute__((address_space(3))) void*)

#define STAGE_A(b, k0) do { \
    unsigned char* _d = smem + (b) * 8192 + wave * 2048; \
    __builtin_amdgcn_global_load_lds(AS1C(aSrc + (k0)),           AS3C(_d),        16, 0, 0); \
    __builtin_amdgcn_global_load_lds(AS1C(aSrc + 16 * GK + (k0)), AS3C(_d + 1024), 16, 0, 0); \
} while (0)
#define STAGE_B(b, k0) do { \
    unsigned char* _d = smem + 24576 + (b) * 8192 + wave * 2048; \
    __builtin_amdgcn_global_load_lds(AS1C(bSrc + (k0)),           AS3C(_d),        16, 0, 0); \
    __builtin_amdgcn_global_load_lds(AS1C(bSrc + 16 * GK + (k0)), AS3C(_d + 1024), 16, 0, 0); \
} while (0)

#define KITER(a, b) do { \
    const unsigned char* As_ = smem + (a) * 8192; \
    const unsigned char* Bs_ = smem + 24576 + (b) * 8192; \
    intx4 af[4], bfr[4]; \
    _Pragma("unroll") \
    for (int _u = 0; _u < 4; ++_u) \
        bfr[_u] = *(const intx4*)(Bs_ + bOff + _u * 1024); \
    _Pragma("unroll") \
    for (int _m = 0; _m < 4; ++_m) \
        af[_m] = *(const intx4*)(As_ + aOff + _m * 1024); \
    _Pragma("unroll") \
    for (int _t = 0; _t < 4; ++_t) \
        _Pragma("unroll") \
        for (int _u = 0; _u < 4; ++_u) \
            acc[_t][_u] = __builtin_amdgcn_mfma_i32_16x16x64_i8( \
                af[_t], bfr[_u], acc[_t][_u], 0, 0, 0); \
} while (0)

#define VM2BAR() asm volatile("s_waitcnt vmcnt(2)\n\ts_barrier" ::: "memory")
#define VM0BAR() asm volatile("s_waitcnt vmcnt(0)\n\ts_barrier" ::: "memory")

__global__ __launch_bounds__(256, 4)
void gemm_all(const unsigned char* __restrict__ postq, const unsigned char* __restrict__ brandq,
              const float* __restrict__ dvec,
              const float* __restrict__ inv_post, const float* __restrict__ inv_brand,
              float* __restrict__ sum_post, float* __restrict__ cnt_post,
              float* __restrict__ sum_brand, float* __restrict__ cnt_brand) {
    __shared__ __align__(16) unsigned char smem[(3 + 2) * BM * BK];   // 40 KB; epilogue alias

    const int tid = threadIdx.x;
    const int wave = tid >> 6, lane = tid & 63;
    const int wm = (wave >> 1) * 64, wn = (wave & 1) * 64;

    int idx = blockIdx.x;

    const unsigned char *A, *B;
    const float *invA, *invB;
    float *srow, *scol, *crow, *ccol;
    int bm, bn;
    float iaScale;
    bool is_cross, do_cols;

    if (idx < NCROSS) {
        is_cross = true; do_cols = true;
        bm = (idx >> 5) * BM; bn = (idx & 31) * BN;
        A = postq; B = brandq;
        invA = inv_post; invB = inv_brand; iaScale = INVT;
        srow = sum_post; crow = cnt_post; scol = sum_brand; ccol = cnt_brand;
    } else {
        is_cross = false;
        idx -= NCROSS;
        const unsigned char* X; const float* invx; float* sacc;
        if (idx >= NTILES) { idx -= NTILES; X = brandq; invx = inv_brand; sacc = sum_brand; }
        else               {               X = postq;  invx = inv_post;  sacc = sum_post;  }
        int J = (int)((sqrtf(8.f * idx + 1.f) - 1.f) * 0.5f);
        while ((J + 1) * (J + 2) / 2 <= idx) ++J;
        while (J * (J + 1) / 2 > idx) --J;
        const int I = idx - J * (J + 1) / 2;
        bm = I * BM; bn = J * BN;
        A = X; B = X;
        invA = invx; invB = invx; iaScale = 0.8f * INVT;
        srow = sacc; scol = sacc; crow = nullptr; ccol = nullptr;
        do_cols = (I != J);
    }

    const int lrow = lane & 15;
    const int kq = lane >> 4;                 // 0..3

    // DMA: lane l -> row l>>2 (16 rows/instr), LDS slot l&3 (linear dest),
    // global chunk (l&3)^((l>>3)&3) = slot ^ ((row>>1)&3), row = base16 + (l>>2).
    const size_t dma_off = (size_t)(lane >> 2) * GK
                         + ((((lane & 3) ^ ((lane >> 3) & 3))) * 16);
    const unsigned char* aSrc = A + (size_t)(bm + wave * 32) * GK + dma_off;
    const unsigned char* bSrc = B + (size_t)(bn + wave * 32) * GK + dma_off;

    // fragment read: row = (wm|wn) + m*16 + lrow -> (row>>1)&3 = (lrow>>1)&3
    const int cx = ((kq ^ ((lrow >> 1) & 3)) * 16);
    const int aOff = (wm + lrow) * BK + cx;
    const int bOff = (wn + lrow) * BK + cx;

    intx4 acc[4][4] = {};

    // prologue: B(0)->b0, A(0)->a0, A(1)->a1; retire B0+A0, leave A1 in flight
    STAGE_B(0, 0); STAGE_A(0, 0); STAGE_A(1, 64);
    VM2BAR();

    // steady state: t = 0..11 (A bufs t%3, B bufs t&1; period lcm = 6)
    #pragma unroll 1
    for (int k = 0; k < 768; k += 384) {
        STAGE_B(1, k +  64); STAGE_A(2, k + 128); KITER(0, 0); VM2BAR();
        STAGE_B(0, k + 128); STAGE_A(0, k + 192); KITER(1, 1); VM2BAR();
        STAGE_B(1, k + 192); STAGE_A(1, k + 256); KITER(2, 0); VM2BAR();
        STAGE_B(0, k + 256); STAGE_A(2, k + 320); KITER(0, 1); VM2BAR();
        STAGE_B(1, k + 320); STAGE_A(0, k + 384); KITER(1, 0); VM2BAR();
        STAGE_B(0, k + 384); STAGE_A(1, k + 448); KITER(2, 1); VM2BAR();
    }
    // tail: t = 12..15
    STAGE_B(1, 832); STAGE_A(2, 896); KITER(0, 0); VM2BAR();   // t=12
    STAGE_B(0, 896); STAGE_A(0, 960); KITER(1, 1); VM2BAR();   // t=13
    STAGE_B(1, 960);                  KITER(2, 0); VM0BAR();   // t=14
                                      KITER(0, 1);             // t=15
    __syncthreads();                  // separates tile reads from epilogue alias

    // ---- epilogue (C/D: col=lane&15, row=(lane>>4)*4+reg; shape-determined) ----
    const int cn = lane & 15, rq = lane >> 4;
    float ib_c[4], db_c[4];
    #pragma unroll
    for (int u = 0; u < 4; ++u) {
        const int gc = bn + wn + u * 16 + cn;
        ib_c[u] = invB[gc];
        db_c[u] = is_cross ? dvec[gc] : 0.f;
    }

    float csum[4] = {}, ccnt[4] = {};
    float my_rs = 0.f, my_rc = 0.f;
    #pragma unroll
    for (int t = 0; t < 4; ++t) {
        #pragma unroll
        for (int r = 0; r < 4; ++r) {
            const int rl = wm + t * 16 + rq * 4 + r;
            const int grow = bm + rl;
            const float ia = invA[grow] * iaScale;
            float v = 0.f, w = 0.f;
            if (is_cross) {
                const float da = dvec[grow];
                #pragma unroll
                for (int u = 0; u < 4; ++u) {
                    const float s = (float)acc[t][u][r];   // exact int < 2^24
                    const int gcol = bn + wn + u * 16 + cn;
                    const bool diag = (grow == gcol);
                    float e = __expf(s * ia * ib_c[u]);
                    v += e;
                    csum[u] += e;
                    w += (!diag && s > da) ? 1.f : 0.f;
                    ccnt[u] += (!diag && s > db_c[u]) ? 1.f : 0.f;
                }
                w += __shfl_xor(w, 1); w += __shfl_xor(w, 2);
                w += __shfl_xor(w, 4); w += __shfl_xor(w, 8);
            } else {
                #pragma unroll
                for (int u = 0; u < 4; ++u) {
                    const float s = (float)acc[t][u][r];
                    const int gcol = bn + wn + u * 16 + cn;
                    float e = (grow == gcol) ? 1.0f : __expf(s * ia * ib_c[u]);
                    v += e;
                    csum[u] += e;
                }
            }
            v += __shfl_xor(v, 1); v += __shfl_xor(v, 2);
            v += __shfl_xor(v, 4); v += __shfl_xor(v, 8);
            if (cn == ((t << 2) | r)) { my_rs = v; my_rc = w; }
        }
    }

    // reduction scratch aliases the (dead) tile LDS
    float (*redRS)[2] = (float(*)[2])(smem);
    float (*redRC)[2] = (float(*)[2])(smem + 1024);
    float (*redCS)[2] = (float(*)[2])(smem + 2048);
    float (*redCC)[2] = (float(*)[2])(smem + 3072);

    const int rl_local = wm + (cn >> 2) * 16 + rq * 4 + (cn & 3);
    redRS[rl_local][wave & 1] = my_rs;
    redRC[rl_local][wave & 1] = my_rc;

    float my_cs = 0.f, my_cc = 0.f;
    #pragma unroll
    for (int u = 0; u < 4; ++u) {
        float v = csum[u];
        v += __shfl_xor(v, 16); v += __shfl_xor(v, 32);
        if (rq == u) my_cs = v;
        if (is_cross) {
            float w = ccnt[u];
            w += __shfl_xor(w, 16); w += __shfl_xor(w, 32);
            if (rq == u) my_cc = w;
        }
    }
    const int cl_local = wn + rq * 16 + cn;
    redCS[cl_local][wave >> 1] = my_cs;
    redCC[cl_local][wave >> 1] = my_cc;
    __syncthreads();

    if (tid < 128) {
        atomicAdd(&srow[bm + tid], redRS[tid][0] + redRS[tid][1]);
        if (is_cross) atomicAdd(&crow[bm + tid], redRC[tid][0] + redRC[tid][1]);
    } else if (do_cols) {
        const int t2 = tid - 128;
        atomicAdd(&scol[bn + t2], redCS[t2][0] + redCS[t2][1]);
        if (is_cross) atomicAdd(&ccol[bn + t2], redCC[t2][0] + redCC[t2][1]);
    }
}

// Final per-row loss assembly + global sum
__global__ __launch_bounds__(256)
void final_loss(const float* __restrict__ sum_post, const float* __restrict__ cnt_post,
                const float* __restrict__ sum_brand, const float* __restrict__ cnt_brand,
                const float* __restrict__ dvec,
                const float* __restrict__ inv_post, const float* __restrict__ inv_brand,
                float* __restrict__ out) {
    const int i = blockIdx.x * 256 + threadIdx.x;
    float dl = dvec[i] * inv_post[i] * inv_brand[i] * INVT;
    float lp = logf(sum_post[i]);
    float lb = logf(sum_brand[i]);
    float rp = 1.0f / (4096.0f - cnt_post[i]) + 1.0f;
    float rb = 1.0f / (4096.0f - cnt_brand[i]) + 1.0f;
    float loss = 0.5f * (rb * (lb - dl) + rp * (lp - dl));
    #pragma unroll
    for (int off = 32; off > 0; off >>= 1) loss += __shfl_down(loss, off);
    __shared__ float sw[4];
    int wave = threadIdx.x >> 6, lane = threadIdx.x & 63;
    if (lane == 0) sw[wave] = loss;
    __syncthreads();
    if (threadIdx.x == 0) atomicAdd(out, sw[0] + sw[1] + sw[2] + sw[3]);
}

extern "C" void kernel_launch(void* const* d_in, const int* in_sizes, int n_in,
                              void* d_out, int out_size, void* d_ws, size_t ws_size,
                              hipStream_t stream) {
    const float* brand = (const float*)d_in[0];
    const float* post  = (const float*)d_in[1];
    float* out = (float*)d_out;

    char* ws = (char*)d_ws;
    unsigned char* postq  = (unsigned char*)ws;                          // 4 MB
    unsigned char* brandq = postq + (size_t)GN * GK;                     // 4 MB
    float* inv_post  = (float*)(brandq + (size_t)GN * GK);
    float* inv_brand = inv_post + GN;
    float* dvec      = inv_brand + GN;
    float* accs      = dvec + GN;        // [sum_post, sum_brand, cnt_post, cnt_brand]
    float* sum_post  = accs;
    float* sum_brand = accs + GN;
    float* cnt_post  = accs + 2 * GN;
    float* cnt_brand = accs + 3 * GN;

    prep_all<<<GN / 4, 256, 0, stream>>>(brand, post, brandq, postq,
                                         inv_brand, inv_post, dvec, accs, out);
    gemm_all<<<NWG, 256, 0, stream>>>(postq, brandq, dvec,
                                      inv_post, inv_brand,
                                      sum_post, cnt_post,
                                      sum_brand, cnt_brand);
    final_loss<<<GN / 256, 256, 0, stream>>>(sum_post, cnt_post, sum_brand, cnt_brand,
                                             dvec, inv_post, inv_brand, out);
}